// Round 1
// baseline (1198.083 us; speedup 1.0000x reference)
//
#include <hip/hip_runtime.h>

typedef short short8 __attribute__((ext_vector_type(8)));
typedef float floatx16 __attribute__((ext_vector_type(16)));
typedef unsigned short u16;

#define BATCH 256
#define FEAT 768
#define NBALLS 1500
#define NCLS 150
#define NTRI 294528
#define SN 1504          // padded column stride of S (>=1500, 16B aligned)
#define NCOL 320         // 256 ood cols + 64 batch slots
#define BETA_C 0.1f

__device__ __forceinline__ u16 f2bf(float f) {
    unsigned u = __float_as_uint(f);
    unsigned r = u + 0x7FFFu + ((u >> 16) & 1u);
    return (u16)(r >> 16);
}

// packed bf16x2 subtract with RNE repack
__device__ __forceinline__ unsigned bf16sub2(unsigned a, unsigned b) {
    float lo = __uint_as_float(a << 16) - __uint_as_float(b << 16);
    float hi = __uint_as_float(a & 0xFFFF0000u) - __uint_as_float(b & 0xFFFF0000u);
    unsigned ul = __float_as_uint(lo); ul = (ul + 0x7FFFu + ((ul >> 16) & 1u)) >> 16;
    unsigned uh = __float_as_uint(hi); uh = (uh + 0x7FFFu + ((uh >> 16) & 1u)) & 0xFFFF0000u;
    return uh | ul;
}

// ---------------- prep: fp32 -> bf16 conversions + zero accumulators ----------------
__global__ void k_prep(const float* __restrict__ pooled, const float* __restrict__ ood,
                       const float* __restrict__ cent,
                       u16* __restrict__ pooled_bf, u16* __restrict__ ood_bf,
                       u16* __restrict__ cent_bf,
                       float* __restrict__ euc2_ood, float* __restrict__ euc2_main,
                       int* __restrict__ bcount) {
    int tid = blockIdx.x * blockDim.x + threadIdx.x;
    int stride = gridDim.x * blockDim.x;
    for (int i = tid; i < BATCH * FEAT; i += stride) {
        pooled_bf[i] = f2bf(pooled[i]);
        ood_bf[i]    = f2bf(ood[i]);
    }
    for (int i = tid; i < NBALLS * FEAT; i += stride) cent_bf[i] = f2bf(cent[i]);
    for (int i = tid; i < NCLS * BATCH; i += stride) euc2_ood[i] = 0.f;
    for (int i = tid; i < BATCH; i += stride) euc2_main[i] = 0.f;
    for (int i = tid; i < NCLS; i += stride) bcount[i] = 0;
}

// ---------------- centroid squared norms (fp32), one wave per centroid ----------------
__global__ void k_cnorm(const float* __restrict__ cent, float* __restrict__ cnorm) {
    int cid = blockIdx.x * 4 + (threadIdx.x >> 6);
    int lane = threadIdx.x & 63;
    const float* row = cent + (size_t)cid * FEAT;
    float s = 0.f;
#pragma unroll
    for (int q = 0; q < FEAT / 64; ++q) { float v = row[lane + q * 64]; s += v * v; }
    for (int o = 32; o > 0; o >>= 1) s += __shfl_down(s, o);
    if (lane == 0) cnorm[cid] = s;
}

// ---------------- deterministic per-class ball lists ----------------
__global__ void k_build_lists(const int* __restrict__ ball_labels,
                              int* __restrict__ cls_cnt, int* __restrict__ cls_list) {
    int k = threadIdx.x;
    if (k >= NCLS) return;
    int cnt = 0;
    for (int n = 0; n < NBALLS; ++n) {
        if (ball_labels[n] == k) {
            if (cnt < 32) cls_list[k * 32 + cnt] = n;
            ++cnt;
        }
    }
    cls_cnt[k] = cnt < 32 ? cnt : 32;
}

// ---------------- S[r][n] = ||c_n||^2 - 2 * q_r . c_n  (bf16 MFMA GEMM) ----------------
// rows 0..255 = pooled, 256..511 = ood.  monotone surrogate of distance per row.
__global__ __launch_bounds__(256) void k_gemm_s(
    const u16* __restrict__ pooled_bf, const u16* __restrict__ ood_bf,
    const u16* __restrict__ cent_bf, const float* __restrict__ cnorm,
    float* __restrict__ S) {
    __shared__ u16 Aq[64 * 40];
    __shared__ u16 Bc[128 * 40];
    const int t = threadIdx.x;
    const int r0 = blockIdx.x * 64;
    const int n0 = blockIdx.y * 128;
    const int w = t >> 6, lane = t & 63;
    const int ml = lane & 31, kh = lane >> 5;
    const int rt = w & 1, cg = w >> 1;

    floatx16 acc[2];
#pragma unroll
    for (int ct = 0; ct < 2; ++ct)
#pragma unroll
        for (int e = 0; e < 16; ++e) acc[ct][e] = 0.f;

    // staging assignments
    const int ar = t >> 2, aj = (t & 3) * 8;        // A: row, 8-elem chunk
    const int rg = r0 + ar;
    const u16* asrc = (rg < BATCH) ? (pooled_bf + (size_t)rg * FEAT)
                                   : (ood_bf + (size_t)(rg - BATCH) * FEAT);
    const int bcn = t >> 1, bj = (t & 1) * 16;      // B: col, 16-elem chunk
    const int ng = n0 + bcn;
    const u16* bsrc = cent_bf + (size_t)(ng < NBALLS ? ng : 0) * FEAT;
    const bool bvalid = (ng < NBALLS);

    for (int k0 = 0; k0 < FEAT; k0 += 32) {
        uint4 av = *(const uint4*)(asrc + k0 + aj);
        *(uint4*)&Aq[ar * 40 + aj] = av;
        uint4 b0, b1;
        if (bvalid) {
            b0 = *(const uint4*)(bsrc + k0 + bj);
            b1 = *(const uint4*)(bsrc + k0 + bj + 8);
        } else { b0 = make_uint4(0,0,0,0); b1 = make_uint4(0,0,0,0); }
        *(uint4*)&Bc[bcn * 40 + bj] = b0;
        *(uint4*)&Bc[bcn * 40 + bj + 8] = b1;
        __syncthreads();
#pragma unroll
        for (int ks = 0; ks < 2; ++ks) {
            short8 a = *(const short8*)&Aq[(rt * 32 + ml) * 40 + ks * 16 + kh * 8];
#pragma unroll
            for (int ct = 0; ct < 2; ++ct) {
                short8 b = *(const short8*)&Bc[((cg * 2 + ct) * 32 + ml) * 40 + ks * 16 + kh * 8];
                acc[ct] = __builtin_amdgcn_mfma_f32_32x32x16_bf16(a, b, acc[ct], 0, 0, 0);
            }
        }
        __syncthreads();
    }
#pragma unroll
    for (int ct = 0; ct < 2; ++ct) {
        int colg = n0 + (cg * 2 + ct) * 32 + ml;
        if (colg >= SN) continue;
        float cn = (colg < NBALLS) ? cnorm[colg] : 0.f;
#pragma unroll
        for (int reg = 0; reg < 16; ++reg) {
            int row = (reg & 3) + 8 * (reg >> 2) + 4 * kh;
            int rgl = r0 + rt * 32 + row;
            S[(size_t)rgl * SN + colg] = cn - 2.f * acc[ct][reg];
        }
    }
}

// ---------------- main-branch argmin over same-class balls + batch lists ----------------
__global__ void k_argmin_main(const float* __restrict__ S, const int* __restrict__ labels,
                              const int* __restrict__ cls_cnt, const int* __restrict__ cls_list,
                              int* __restrict__ ball_ids, int* __restrict__ bcount,
                              int* __restrict__ blist) {
    int b = threadIdx.x;
    if (b >= BATCH) return;
    int k = labels[b];
    if (k < 0) k = 0; if (k >= NCLS) k = NCLS - 1;
    int cnt = cls_cnt[k];
    float best = 3.4e38f; int bestn = 0;
    for (int tt = 0; tt < cnt; ++tt) {
        int n = cls_list[k * 32 + tt];
        float v = S[(size_t)b * SN + n];
        if (v < best) { best = v; bestn = n; }
    }
    ball_ids[b] = bestn;
    int slot = atomicAdd(&bcount[k], 1);
    if (slot < 64) blist[k * 64 + slot] = b;
}

// ---------------- ood-branch per-(class, m) argmin ----------------
__global__ void k_argmin_ood(const float* __restrict__ S, const int* __restrict__ cls_cnt,
                             const int* __restrict__ cls_list, int* __restrict__ nearidx) {
    int k = blockIdx.x, m = threadIdx.x;
    int cnt = cls_cnt[k];
    float best = 3.4e38f; int bestn = 0;
    for (int tt = 0; tt < cnt; ++tt) {
        int n = cls_list[k * 32 + tt];
        float v = S[(size_t)(BATCH + m) * SN + n];
        if (v < best) { best = v; bestn = n; }
    }
    nearidx[k * BATCH + m] = bestn;
}

// ---------------- THE big kernel: per-class fused R-build + GEMM + col-norm ----------------
// grid: x = 6 row-slices of 128, y = 150 classes. 256 threads.
// Y = R_k @ X, X = [ood - c_near(k,m) | pooled_b - c_ball(b) (class-k batch) | 0-pad]
// epilogue: euc2 accumulation of column squared norms via atomics.
__global__ __launch_bounds__(256, 2) void k_gemm2(
    const float* __restrict__ Lp, const float* __restrict__ Up, const float* __restrict__ Ddp,
    const u16* __restrict__ pooled_bf, const u16* __restrict__ ood_bf,
    const u16* __restrict__ cent_bf,
    const int* __restrict__ nearidx, const int* __restrict__ bcount,
    const int* __restrict__ blist, const int* __restrict__ ball_ids,
    float* __restrict__ euc2_ood, float* __restrict__ euc2_main) {
    __shared__ u16 At[128 * 40];
    __shared__ u16 Bt[NCOL * 40];
    const int t = threadIdx.x;
    const int i0 = blockIdx.x * 128;
    const int k = blockIdx.y;
    const float* Lr = Lp + (size_t)k * NTRI;
    const float* Ur = Up + (size_t)k * NTRI;
    const float* Ddr = Ddp + (size_t)k * FEAT;

    // fixed per-thread B-column sources
    const int nr = nearidx[k * BATCH + t];
    const u16* srcO = ood_bf + (size_t)t * FEAT;
    const u16* srcC = cent_bf + (size_t)nr * FEAT;
    const int bc = bcount[k];
    const bool has2 = (t < 64);
    bool valid2 = false;
    const u16 *srcO2 = pooled_bf, *srcC2 = cent_bf;
    if (has2 && t < bc) {
        int b = blist[k * 64 + t];
        srcO2 = pooled_bf + (size_t)b * FEAT;
        srcC2 = cent_bf + (size_t)ball_ids[b] * FEAT;
        valid2 = true;
    }

    const int w = t >> 6, lane = t & 63;
    const int ml = lane & 31, kh = lane >> 5;

    floatx16 acc[10];
#pragma unroll
    for (int ct = 0; ct < 10; ++ct)
#pragma unroll
        for (int e = 0; e < 16; ++e) acc[ct][e] = 0.f;

    for (int j0 = 0; j0 < FEAT; j0 += 32) {
        // ---- stage A = R_k[i0:i0+128, j0:j0+32] as bf16 ----
        if (j0 + 32 <= i0) {               // strictly lower triangle -> L, row-contiguous
#pragma unroll
            for (int p = 0; p < 16; ++p) {
                int idx = t + p * 256;
                int r = idx >> 5, j = idx & 31;
                int i = i0 + r;
                float v = Lr[(unsigned)(i * (i - 1) / 2) + j0 + j];
                At[r * 40 + j] = f2bf(v);
            }
        } else if (j0 >= i0 + 128) {       // strictly upper -> U, col-contiguous (in i)
#pragma unroll
            for (int p = 0; p < 16; ++p) {
                int idx = t + p * 256;
                int i = idx & 127, jj = idx >> 7;
                int j = j0 + jj;
                float v = Ur[(unsigned)(j * (j - 1) / 2) + i0 + i];
                At[i * 40 + jj] = f2bf(v);
            }
        } else {                           // diagonal band: per-element
#pragma unroll
            for (int p = 0; p < 16; ++p) {
                int idx = t + p * 256;
                int r = idx >> 5, j = idx & 31;
                int i = i0 + r, jg = j0 + j;
                float v;
                if (i > jg)       v = Lr[(unsigned)(i * (i - 1) / 2) + jg];
                else if (i < jg)  v = Ur[(unsigned)(jg * (jg - 1) / 2) + i];
                else              v = Ddr[i];
                At[r * 40 + j] = f2bf(v);
            }
        }
        // ---- stage B: X columns (bf16 subtract) ----
        {
            const u16* o = srcO + j0;
            const u16* c = srcC + j0;
#pragma unroll
            for (int q = 0; q < 4; ++q) {
                uint4 ov = *(const uint4*)(o + q * 8);
                uint4 cv = *(const uint4*)(c + q * 8);
                uint4 rv;
                rv.x = bf16sub2(ov.x, cv.x); rv.y = bf16sub2(ov.y, cv.y);
                rv.z = bf16sub2(ov.z, cv.z); rv.w = bf16sub2(ov.w, cv.w);
                *(uint4*)&Bt[t * 40 + q * 8] = rv;
            }
            if (has2) {
                int col = 256 + t;
                if (valid2) {
                    const u16* o2 = srcO2 + j0;
                    const u16* c2 = srcC2 + j0;
#pragma unroll
                    for (int q = 0; q < 4; ++q) {
                        uint4 ov = *(const uint4*)(o2 + q * 8);
                        uint4 cv = *(const uint4*)(c2 + q * 8);
                        uint4 rv;
                        rv.x = bf16sub2(ov.x, cv.x); rv.y = bf16sub2(ov.y, cv.y);
                        rv.z = bf16sub2(ov.z, cv.z); rv.w = bf16sub2(ov.w, cv.w);
                        *(uint4*)&Bt[col * 40 + q * 8] = rv;
                    }
                } else {
                    uint4 z = make_uint4(0, 0, 0, 0);
#pragma unroll
                    for (int q = 0; q < 4; ++q) *(uint4*)&Bt[col * 40 + q * 8] = z;
                }
            }
        }
        __syncthreads();
        // ---- MFMA: wave w owns rows i0 + w*32 .. +32, all 320 cols ----
#pragma unroll
        for (int ks = 0; ks < 2; ++ks) {
            short8 a = *(const short8*)&At[(w * 32 + ml) * 40 + ks * 16 + kh * 8];
#pragma unroll
            for (int ct = 0; ct < 10; ++ct) {
                short8 b = *(const short8*)&Bt[(ct * 32 + ml) * 40 + ks * 16 + kh * 8];
                acc[ct] = __builtin_amdgcn_mfma_f32_32x32x16_bf16(a, b, acc[ct], 0, 0, 0);
            }
        }
        __syncthreads();
    }

    // ---- epilogue: per-column sum of squares over this 128-row slice ----
#pragma unroll
    for (int ct = 0; ct < 10; ++ct) {
        float s = 0.f;
#pragma unroll
        for (int reg = 0; reg < 16; ++reg) { float v = acc[ct][reg]; s += v * v; }
        s += __shfl_xor(s, 32);
        if (kh == 0) {
            int col = ct * 32 + ml;
            if (col < 256) {
                atomicAdd(&euc2_ood[k * BATCH + col], s);
            } else {
                int tt = col - 256;
                if (tt < bc && tt < 64) atomicAdd(&euc2_main[blist[k * 64 + tt]], s);
            }
        }
    }
}

// ---------------- final loss assembly ----------------
__global__ void k_final(const float* __restrict__ euc2_main, const float* __restrict__ euc2_ood,
                        const int* __restrict__ ball_ids, const int* __restrict__ nearidx,
                        const float* __restrict__ delta, float* __restrict__ out) {
    __shared__ float red[256];
    int t = threadIdx.x;

    float euc = sqrtf(euc2_main[t]);
    float d = delta[ball_ids[t]];
    float pl = (d > euc) ? expf(euc - d) : (euc - d);
    float pn = (euc > d) ? 1.f : 0.f;
    float nn = (euc < d) ? 1.f : 0.f;

    float s = 0.f;
    for (int k = 0; k < NCLS; ++k) {
        int idx = k * BATCH + t;
        float e = sqrtf(euc2_ood[idx]);
        float dn = delta[nearidx[idx]];
        s += (dn > e) ? (dn - e + BETA_C) : (BETA_C * expf(dn - e));
    }

    auto reduce = [&](float v) -> float {
        red[t] = v; __syncthreads();
        for (int o = 128; o > 0; o >>= 1) {
            if (t < o) red[t] += red[t + o];
            __syncthreads();
        }
        float r = red[0]; __syncthreads();
        return r;
    };
    float pos_sum = reduce(pl);
    float pnum    = reduce(pn);
    float nnum    = reduce(nn);
    float neg_sum = reduce(s);
    if (t == 0) {
        float pos_mean = pos_sum / (float)BATCH;
        float neg_mean = neg_sum / (float)BATCH;
        out[0] = pos_mean;
        out[1] = neg_mean;
        out[2] = pnum;
        out[3] = nnum;
        out[4] = pos_mean + neg_mean;
    }
}

extern "C" void kernel_launch(void* const* d_in, const int* in_sizes, int n_in,
                              void* d_out, int out_size, void* d_ws, size_t ws_size,
                              hipStream_t stream) {
    const float* pooled      = (const float*)d_in[0];
    const float* ood         = (const float*)d_in[1];
    const float* cent        = (const float*)d_in[2];
    const float* delta       = (const float*)d_in[3];
    const float* L           = (const float*)d_in[4];
    const float* U           = (const float*)d_in[5];
    const float* Dd          = (const float*)d_in[6];
    const int*   labels      = (const int*)d_in[7];
    const int*   ball_labels = (const int*)d_in[8];
    float* out = (float*)d_out;

    char* base = (char*)d_ws;
    size_t off = 0;
    auto carve = [&](size_t bytes) -> void* {
        off = (off + 255) & ~(size_t)255;
        void* p = base + off;
        off += bytes;
        return p;
    };
    u16*   pooled_bf = (u16*)carve((size_t)BATCH * FEAT * 2);
    u16*   ood_bf    = (u16*)carve((size_t)BATCH * FEAT * 2);
    u16*   cent_bf   = (u16*)carve((size_t)NBALLS * FEAT * 2);
    float* cnorm     = (float*)carve((size_t)SN * 4);
    float* S         = (float*)carve((size_t)512 * SN * 4);
    int*   cls_cnt   = (int*)carve((size_t)NCLS * 4);
    int*   cls_list  = (int*)carve((size_t)NCLS * 32 * 4);
    int*   ball_ids  = (int*)carve((size_t)BATCH * 4);
    int*   bcount    = (int*)carve((size_t)NCLS * 4);
    int*   blist     = (int*)carve((size_t)NCLS * 64 * 4);
    int*   nearidx   = (int*)carve((size_t)NCLS * BATCH * 4);
    float* euc2_ood  = (float*)carve((size_t)NCLS * BATCH * 4);
    float* euc2_main = (float*)carve((size_t)BATCH * 4);

    k_prep<<<1024, 256, 0, stream>>>(pooled, ood, cent, pooled_bf, ood_bf, cent_bf,
                                     euc2_ood, euc2_main, bcount);
    k_cnorm<<<NBALLS / 4, 256, 0, stream>>>(cent, cnorm);
    k_build_lists<<<1, 256, 0, stream>>>(ball_labels, cls_cnt, cls_list);
    k_gemm_s<<<dim3(8, 12), 256, 0, stream>>>(pooled_bf, ood_bf, cent_bf, cnorm, S);
    k_argmin_main<<<1, 256, 0, stream>>>(S, labels, cls_cnt, cls_list, ball_ids, bcount, blist);
    k_argmin_ood<<<NCLS, 256, 0, stream>>>(S, cls_cnt, cls_list, nearidx);
    k_gemm2<<<dim3(6, NCLS), 256, 0, stream>>>(L, U, Dd, pooled_bf, ood_bf, cent_bf,
                                               nearidx, bcount, blist, ball_ids,
                                               euc2_ood, euc2_main);
    k_final<<<1, 256, 0, stream>>>(euc2_main, euc2_ood, ball_ids, nearidx, delta, out);
}

// Round 2
// 610.887 us; speedup vs baseline: 1.9612x; 1.9612x over previous
//
#include <hip/hip_runtime.h>

typedef short short8 __attribute__((ext_vector_type(8)));
typedef float floatx16 __attribute__((ext_vector_type(16)));
typedef unsigned short u16;

#define BATCH 256
#define FEAT 768
#define NBALLS 1500
#define NCLS 150
#define NTRI 294528
#define SN 1504          // padded column stride of S
#define NCOL 320         // 256 ood cols + 64 batch slots
#define NSLICE 12        // 12 x 64-row slices of the 768 output rows
#define BETA_C 0.1f

__device__ __forceinline__ u16 f2bf(float f) {
    unsigned u = __float_as_uint(f);
    return (u16)((u + 0x7FFFu + ((u >> 16) & 1u)) >> 16);
}
__device__ __forceinline__ unsigned pack2bf(float lo, float hi) {
    unsigned ul = __float_as_uint(lo); ul = (ul + 0x7FFFu + ((ul >> 16) & 1u)) >> 16;
    unsigned uh = __float_as_uint(hi); uh = (uh + 0x7FFFu + ((uh >> 16) & 1u)) & 0xFFFF0000u;
    return uh | ul;
}
__device__ __forceinline__ unsigned bf16sub2(unsigned a, unsigned b) {
    float lo = __uint_as_float(a << 16) - __uint_as_float(b << 16);
    float hi = __uint_as_float(a & 0xFFFF0000u) - __uint_as_float(b & 0xFFFF0000u);
    unsigned ul = __float_as_uint(lo); ul = (ul + 0x7FFFu + ((ul >> 16) & 1u)) >> 16;
    unsigned uh = __float_as_uint(hi); uh = (uh + 0x7FFFu + ((uh >> 16) & 1u)) & 0xFFFF0000u;
    return uh | ul;
}

// ---------------- fused prep: bf16 conversion + centroid norms + class lists + zeroing ----
// blocks [0,1037): all run grid-stride conversions; [512,887) also cnorm; [887,1037) also lists
__global__ __launch_bounds__(256) void k_prep(
    const float* __restrict__ pooled, const float* __restrict__ ood,
    const float* __restrict__ cent, const int* __restrict__ ball_labels,
    u16* __restrict__ xsrc, u16* __restrict__ cent_bf, float* __restrict__ cnorm,
    int* __restrict__ cls_cnt, int* __restrict__ cls_list,
    float* __restrict__ euc2_main, int* __restrict__ bcount) {
    __shared__ int scnt;
    const int t = threadIdx.x, blk = blockIdx.x;
    const int tid = blk * 256 + t, stride = gridDim.x * 256;
    uint2* xp = (uint2*)xsrc;                       // pooled -> rows 0..255
    for (int i = tid; i < (BATCH * FEAT) / 4; i += stride) {
        const float4 v = ((const float4*)pooled)[i];
        xp[i] = make_uint2(pack2bf(v.x, v.y), pack2bf(v.z, v.w));
    }
    uint2* xo = (uint2*)(xsrc + BATCH * FEAT);      // ood -> rows 256..511
    for (int i = tid; i < (BATCH * FEAT) / 4; i += stride) {
        const float4 v = ((const float4*)ood)[i];
        xo[i] = make_uint2(pack2bf(v.x, v.y), pack2bf(v.z, v.w));
    }
    uint2* cd = (uint2*)cent_bf;
    for (int i = tid; i < (NBALLS * FEAT) / 4; i += stride) {
        const float4 v = ((const float4*)cent)[i];
        cd[i] = make_uint2(pack2bf(v.x, v.y), pack2bf(v.z, v.w));
    }
    for (int i = tid; i < BATCH; i += stride) euc2_main[i] = 0.f;
    for (int i = tid; i < NCLS; i += stride) bcount[i] = 0;

    if (blk >= 512 && blk < 512 + 375) {            // centroid squared norms, 4 waves/block
        int cid = (blk - 512) * 4 + (t >> 6);
        int lane = t & 63;
        const float* row = cent + (size_t)cid * FEAT;
        float s = 0.f;
#pragma unroll
        for (int q = 0; q < FEAT / 64; ++q) { float v = row[lane + q * 64]; s += v * v; }
        for (int o = 32; o > 0; o >>= 1) s += __shfl_down(s, o);
        if (lane == 0) cnorm[cid] = s;
    }
    if (blk >= 887 && blk < 887 + NCLS) {           // per-class ball lists (parallel scan)
        int k = blk - 887;
        if (t == 0) scnt = 0;
        __syncthreads();
        for (int n = t; n < NBALLS; n += 256) {
            if (ball_labels[n] == k) {
                int p = atomicAdd(&scnt, 1);
                if (p < 32) cls_list[k * 32 + p] = n;
            }
        }
        __syncthreads();
        if (t == 0) cls_cnt[k] = scnt < 32 ? scnt : 32;
    }
}

// ---------------- S[r][n] = ||c_n||^2 - 2 q_r . c_n (monotone distance surrogate) --------
__global__ __launch_bounds__(256) void k_gemm_s(
    const u16* __restrict__ xsrc, const u16* __restrict__ cent_bf,
    const float* __restrict__ cnorm, float* __restrict__ S) {
    __shared__ u16 Aq[64 * 40];
    __shared__ u16 Bc[128 * 40];
    const int t = threadIdx.x;
    const int r0 = blockIdx.x * 64;
    const int n0 = blockIdx.y * 128;
    const int w = t >> 6, lane = t & 63;
    const int ml = lane & 31, kh = lane >> 5;
    const int rt = w & 1, cg = w >> 1;

    floatx16 acc[2];
#pragma unroll
    for (int ct = 0; ct < 2; ++ct)
#pragma unroll
        for (int e = 0; e < 16; ++e) acc[ct][e] = 0.f;

    const int ar = t >> 2, aj = (t & 3) * 8;
    const u16* asrc = xsrc + (size_t)(r0 + ar) * FEAT;
    const int bcn = t >> 1, bj = (t & 1) * 16;
    const int ng = n0 + bcn;
    const u16* bsrc = cent_bf + (size_t)(ng < NBALLS ? ng : 0) * FEAT;
    const bool bvalid = (ng < NBALLS);

#pragma unroll 1
    for (int k0 = 0; k0 < FEAT; k0 += 32) {
        uint4 av = *(const uint4*)(asrc + k0 + aj);
        uint4 b0, b1;
        if (bvalid) {
            b0 = *(const uint4*)(bsrc + k0 + bj);
            b1 = *(const uint4*)(bsrc + k0 + bj + 8);
        } else { b0 = make_uint4(0,0,0,0); b1 = make_uint4(0,0,0,0); }
        *(uint4*)&Aq[ar * 40 + aj] = av;
        *(uint4*)&Bc[bcn * 40 + bj] = b0;
        *(uint4*)&Bc[bcn * 40 + bj + 8] = b1;
        __syncthreads();
#pragma unroll
        for (int ks = 0; ks < 2; ++ks) {
            short8 a = *(const short8*)&Aq[(rt * 32 + ml) * 40 + ks * 16 + kh * 8];
#pragma unroll
            for (int ct = 0; ct < 2; ++ct) {
                short8 b = *(const short8*)&Bc[((cg * 2 + ct) * 32 + ml) * 40 + ks * 16 + kh * 8];
                acc[ct] = __builtin_amdgcn_mfma_f32_32x32x16_bf16(a, b, acc[ct], 0, 0, 0);
            }
        }
        __syncthreads();
    }
#pragma unroll
    for (int ct = 0; ct < 2; ++ct) {
        int colg = n0 + (cg * 2 + ct) * 32 + ml;
        if (colg >= SN) continue;
        float cn = (colg < NBALLS) ? cnorm[colg] : 0.f;
#pragma unroll
        for (int reg = 0; reg < 16; ++reg) {
            int row = (reg & 3) + 8 * (reg >> 2) + 4 * kh;
            int rgl = r0 + rt * 32 + row;
            S[(size_t)rgl * SN + colg] = cn - 2.f * acc[ct][reg];
        }
    }
}

// ---------------- fused argmins: block 0 = main branch, blocks 1..150 = ood classes ------
__global__ void k_argmin(const float* __restrict__ S, const int* __restrict__ labels,
                         const int* __restrict__ cls_cnt, const int* __restrict__ cls_list,
                         int* __restrict__ ball_ids, int* __restrict__ bcount,
                         int* __restrict__ blist, int* __restrict__ nearidx) {
    const int t = threadIdx.x;
    if (blockIdx.x == 0) {
        int k = labels[t];
        if (k < 0) k = 0; if (k >= NCLS) k = NCLS - 1;
        int cnt = cls_cnt[k];
        float best = 3.4e38f; int bestn = 0;
        for (int i = 0; i < cnt; ++i) {
            int n = cls_list[k * 32 + i];
            float v = S[(size_t)t * SN + n];
            if (v < best) { best = v; bestn = n; }
        }
        ball_ids[t] = bestn;
        int slot = atomicAdd(&bcount[k], 1);
        if (slot < 64) blist[k * 64 + slot] = t;
    } else {
        int k = blockIdx.x - 1;
        int cnt = cls_cnt[k];
        float best = 3.4e38f; int bestn = 0;
        for (int i = 0; i < cnt; ++i) {
            int n = cls_list[k * 32 + i];
            float v = S[(size_t)(BATCH + t) * SN + n];
            if (v < best) { best = v; bestn = n; }
        }
        nearidx[k * BATCH + t] = bestn;
    }
}

// ---------------- THE big kernel: fused R-build + per-class GEMM + column norms ----------
// grid (12, 150): 64-row slices x classes. Prefetched L/U staging, partial-sum epilogue.
__global__ __launch_bounds__(256, 2) void k_gemm2(
    const float* __restrict__ Lp, const float* __restrict__ Up, const float* __restrict__ Ddp,
    const u16* __restrict__ xsrc, const u16* __restrict__ cent_bf,
    const int* __restrict__ nearidx, const int* __restrict__ bcount,
    const int* __restrict__ blist, const int* __restrict__ ball_ids,
    float* __restrict__ euc2_part) {
    __shared__ u16 At[64 * 40];
    __shared__ u16 Bt[NCOL * 40];
    __shared__ unsigned oidx_s[NCOL];
    __shared__ unsigned cidx_s[NCOL];
    __shared__ float sred[2 * NCOL];

    const int t = threadIdx.x;
    const int slice = blockIdx.x;
    const int i0 = slice * 64;
    const int k = blockIdx.y;
    const float* __restrict__ Lr = Lp + (size_t)k * NTRI;
    const float* __restrict__ Ur = Up + (size_t)k * NTRI;
    const float* __restrict__ Ddr = Ddp + (size_t)k * FEAT;

    int bc = bcount[k]; if (bc > 64) bc = 64;
    oidx_s[t] = 256u + (unsigned)t;                 // ood rows live at xsrc rows 256..511
    cidx_s[t] = (unsigned)nearidx[k * BATCH + t];
    if (t < 64) {
        unsigned oi = 0u, ci = 0xFFFFFFFFu;
        if (t < bc) { int b = blist[k * 64 + t]; oi = (unsigned)b; ci = (unsigned)ball_ids[b]; }
        oidx_s[256 + t] = oi;
        cidx_s[256 + t] = ci;
    }
    __syncthreads();

    const int w = t >> 6, lane = t & 63;
    const int ml = lane & 31, kh = lane >> 5;
    const int rt = w & 1, cg = w >> 1;

    floatx16 acc[5];
#pragma unroll
    for (int cc = 0; cc < 5; ++cc)
#pragma unroll
        for (int e = 0; e < 16; ++e) acc[cc][e] = 0.f;

    float a[8];
    // A staging: 64x32 fp32 elems of R_k -> 8 per thread. Three uniform tile types.
    auto loadA = [&](int j0) {
        if (j0 + 32 <= i0) {                       // pure lower triangle: rows of L
#pragma unroll
            for (int u = 0; u < 2; ++u) {
                const int i = i0 + u * 32 + (t >> 3);
                const float* p = Lr + ((unsigned)(i * (i - 1)) >> 1) + j0 + (t & 7) * 4;
#pragma unroll
                for (int e = 0; e < 4; ++e) a[u * 4 + e] = p[e];
            }
        } else if (j0 >= i0 + 64) {                // pure upper: columns of U (contig in i)
#pragma unroll
            for (int u = 0; u < 2; ++u) {
                const int j = j0 + u * 16 + (t >> 4);
                const float* p = Ur + ((unsigned)(j * (j - 1)) >> 1) + i0 + (t & 15) * 4;
#pragma unroll
                for (int e = 0; e < 4; ++e) a[u * 4 + e] = p[e];
            }
        } else {                                   // diagonal band: per-element select
#pragma unroll
            for (int u = 0; u < 8; ++u) {
                const int idx = u * 256 + t;
                const int i = i0 + (idx >> 5), jg = j0 + (idx & 31);
                float v;
                if (i > jg)      v = Lr[((unsigned)(i * (i - 1)) >> 1) + jg];
                else if (i < jg) v = Ur[((unsigned)(jg * (jg - 1)) >> 1) + i];
                else             v = Ddr[i];
                a[u] = v;
            }
        }
    };
    auto storeA = [&](int j0) {
        if (j0 + 32 <= i0) {
#pragma unroll
            for (int u = 0; u < 2; ++u) {
                const int row = u * 32 + (t >> 3);
                unsigned lo = pack2bf(a[u * 4 + 0], a[u * 4 + 1]);
                unsigned hi = pack2bf(a[u * 4 + 2], a[u * 4 + 3]);
                *(uint2*)&At[row * 40 + (t & 7) * 4] = make_uint2(lo, hi);
            }
        } else if (j0 >= i0 + 64) {
#pragma unroll
            for (int u = 0; u < 2; ++u) {
                const int jj = u * 16 + (t >> 4);
                const int ic = (t & 15) * 4;
#pragma unroll
                for (int e = 0; e < 4; ++e) At[(ic + e) * 40 + jj] = f2bf(a[u * 4 + e]);
            }
        } else {
#pragma unroll
            for (int u = 0; u < 8; ++u) {
                const int idx = u * 256 + t;
                At[(idx >> 5) * 40 + (idx & 31)] = f2bf(a[u]);
            }
        }
    };
    auto stageB = [&](int j0) {                    // 320 cols x 32 k, bf16 subtract (L2-hot)
#pragma unroll
        for (int u = 0; u < 5; ++u) {
            const int g = u * 256 + t;
            const int col = g >> 2, ch = (g & 3) * 8;
            const unsigned ci = cidx_s[col];
            u16* dst = &Bt[col * 40 + ch];
            if (ci == 0xFFFFFFFFu) {
                *(uint4*)dst = make_uint4(0u, 0u, 0u, 0u);
            } else {
                const u16* o = xsrc + (size_t)oidx_s[col] * FEAT + j0 + ch;
                const u16* c = cent_bf + (size_t)ci * FEAT + j0 + ch;
                const uint4 ov = *(const uint4*)o;
                const uint4 cv = *(const uint4*)c;
                uint4 rv;
                rv.x = bf16sub2(ov.x, cv.x); rv.y = bf16sub2(ov.y, cv.y);
                rv.z = bf16sub2(ov.z, cv.z); rv.w = bf16sub2(ov.w, cv.w);
                *(uint4*)dst = rv;
            }
        }
    };

    loadA(0);
#pragma unroll 1
    for (int j0 = 0; j0 < FEAT; j0 += 32) {
        storeA(j0);
        stageB(j0);
        __syncthreads();
        if (j0 + 32 < FEAT) loadA(j0 + 32);        // prefetch: in flight across MFMA + barrier
#pragma unroll
        for (int ks = 0; ks < 2; ++ks) {
            const short8 af = *(const short8*)&At[(rt * 32 + ml) * 40 + ks * 16 + kh * 8];
#pragma unroll
            for (int cc = 0; cc < 5; ++cc) {
                const short8 bv = *(const short8*)&Bt[((cg * 5 + cc) * 32 + ml) * 40 + ks * 16 + kh * 8];
                acc[cc] = __builtin_amdgcn_mfma_f32_32x32x16_bf16(af, bv, acc[cc], 0, 0, 0);
            }
        }
        __syncthreads();
    }

    // per-column sum of squares over this 64-row slice; combine both row-halves via LDS
#pragma unroll
    for (int cc = 0; cc < 5; ++cc) {
        float s = 0.f;
#pragma unroll
        for (int e = 0; e < 16; ++e) { float v = acc[cc][e]; s += v * v; }
        s += __shfl_xor(s, 32);
        if (kh == 0) sred[rt * NCOL + cg * 160 + cc * 32 + ml] = s;
    }
    __syncthreads();
    float* outp = euc2_part + ((size_t)k * NSLICE + slice) * NCOL;
    outp[t] = sred[t] + sred[NCOL + t];
    if (t < 64) outp[256 + t] = sred[256 + t] + sred[NCOL + 256 + t];
}

// ---------------- slice reduction: 12 partials -> euc2 ----------------
__global__ void k_reduce(const float* __restrict__ euc2_part, const int* __restrict__ bcount,
                         const int* __restrict__ blist,
                         float* __restrict__ euc2_ood, float* __restrict__ euc2_main) {
    const int k = blockIdx.x, t = threadIdx.x;
    const float* p = euc2_part + (size_t)k * NSLICE * NCOL;
    float s = 0.f;
#pragma unroll
    for (int s12 = 0; s12 < NSLICE; ++s12) s += p[s12 * NCOL + t];
    euc2_ood[k * BATCH + t] = s;
    if (t < 64) {
        int bc = bcount[k]; if (bc > 64) bc = 64;
        if (t < bc) {
            float s2 = 0.f;
#pragma unroll
            for (int s12 = 0; s12 < NSLICE; ++s12) s2 += p[s12 * NCOL + 256 + t];
            euc2_main[blist[k * 64 + t]] = s2;     // each b appears in exactly one list
        }
    }
}

// ---------------- final loss assembly ----------------
__global__ void k_final(const float* __restrict__ euc2_main, const float* __restrict__ euc2_ood,
                        const int* __restrict__ ball_ids, const int* __restrict__ nearidx,
                        const float* __restrict__ delta, float* __restrict__ out) {
    __shared__ float red[256];
    const int t = threadIdx.x;

    float euc = sqrtf(euc2_main[t]);
    float d = delta[ball_ids[t]];
    float pl = (d > euc) ? expf(euc - d) : (euc - d);
    float pn = (euc > d) ? 1.f : 0.f;
    float nn = (euc < d) ? 1.f : 0.f;

    float s = 0.f;
    for (int k = 0; k < NCLS; ++k) {
        int idx = k * BATCH + t;
        float e = sqrtf(euc2_ood[idx]);
        float dn = delta[nearidx[idx]];
        s += (dn > e) ? (dn - e + BETA_C) : (BETA_C * expf(dn - e));
    }

    auto reduce = [&](float v) -> float {
        red[t] = v; __syncthreads();
        for (int o = 128; o > 0; o >>= 1) {
            if (t < o) red[t] += red[t + o];
            __syncthreads();
        }
        float r = red[0]; __syncthreads();
        return r;
    };
    float pos_sum = reduce(pl);
    float pnum    = reduce(pn);
    float nnum    = reduce(nn);
    float neg_sum = reduce(s);
    if (t == 0) {
        float pos_mean = pos_sum / (float)BATCH;
        float neg_mean = neg_sum / (float)BATCH;
        out[0] = pos_mean;
        out[1] = neg_mean;
        out[2] = pnum;
        out[3] = nnum;
        out[4] = pos_mean + neg_mean;
    }
}

extern "C" void kernel_launch(void* const* d_in, const int* in_sizes, int n_in,
                              void* d_out, int out_size, void* d_ws, size_t ws_size,
                              hipStream_t stream) {
    const float* pooled      = (const float*)d_in[0];
    const float* ood         = (const float*)d_in[1];
    const float* cent        = (const float*)d_in[2];
    const float* delta       = (const float*)d_in[3];
    const float* L           = (const float*)d_in[4];
    const float* U           = (const float*)d_in[5];
    const float* Dd          = (const float*)d_in[6];
    const int*   labels      = (const int*)d_in[7];
    const int*   ball_labels = (const int*)d_in[8];
    float* out = (float*)d_out;

    char* base = (char*)d_ws;
    size_t off = 0;
    auto carve = [&](size_t bytes) -> void* {
        off = (off + 255) & ~(size_t)255;
        void* p = base + off;
        off += bytes;
        return p;
    };
    u16*   xsrc      = (u16*)carve((size_t)512 * FEAT * 2);      // pooled rows 0..255, ood 256..511
    u16*   cent_bf   = (u16*)carve((size_t)NBALLS * FEAT * 2);
    float* cnorm     = (float*)carve((size_t)SN * 4);
    float* S         = (float*)carve((size_t)512 * SN * 4);
    int*   cls_cnt   = (int*)carve((size_t)NCLS * 4);
    int*   cls_list  = (int*)carve((size_t)NCLS * 32 * 4);
    int*   ball_ids  = (int*)carve((size_t)BATCH * 4);
    int*   bcount    = (int*)carve((size_t)NCLS * 4);
    int*   blist     = (int*)carve((size_t)NCLS * 64 * 4);
    int*   nearidx   = (int*)carve((size_t)NCLS * BATCH * 4);
    float* euc2_part = (float*)carve((size_t)NCLS * NSLICE * NCOL * 4);
    float* euc2_ood  = (float*)carve((size_t)NCLS * BATCH * 4);
    float* euc2_main = (float*)carve((size_t)BATCH * 4);

    k_prep<<<1037, 256, 0, stream>>>(pooled, ood, cent, ball_labels, xsrc, cent_bf, cnorm,
                                     cls_cnt, cls_list, euc2_main, bcount);
    k_gemm_s<<<dim3(8, 12), 256, 0, stream>>>(xsrc, cent_bf, cnorm, S);
    k_argmin<<<151, 256, 0, stream>>>(S, labels, cls_cnt, cls_list, ball_ids, bcount, blist, nearidx);
    k_gemm2<<<dim3(NSLICE, NCLS), 256, 0, stream>>>(L, U, Dd, xsrc, cent_bf,
                                                    nearidx, bcount, blist, ball_ids, euc2_part);
    k_reduce<<<NCLS, 256, 0, stream>>>(euc2_part, bcount, blist, euc2_ood, euc2_main);
    k_final<<<1, 256, 0, stream>>>(euc2_main, euc2_ood, ball_ids, nearidx, delta, out);
}